// Round 5
// baseline (371.859 us; speedup 1.0000x reference)
//
#include <hip/hip_runtime.h>

#define B_ 128
#define T_ 256
#define H_ 768
#define K_ 64
#define BT_ (B_ * T_)

// ---------------------------------------------------------------------------
// DPP helpers. wave_rol:1 = 0x134, wave_ror:1 = 0x13C (GCN/CDNA wave-wide
// rotate by one lane, wraps). Direction is probed at runtime, not assumed.
// ---------------------------------------------------------------------------
template <int CTRL>
__device__ __forceinline__ float dpp_mov_f(float x) {
    return __int_as_float(__builtin_amdgcn_update_dpp(
        __float_as_int(x), __float_as_int(x), CTRL, 0xF, 0xF, false));
}
template <int CTRL>
__device__ __forceinline__ int dpp_mov_i(int x) {
    return __builtin_amdgcn_update_dpp(x, x, CTRL, 0xF, 0xF, false);
}
__device__ __forceinline__ float wave_max64(float x) {
    x = fmaxf(x, dpp_mov_f<0x111>(x));  // row_shr:1
    x = fmaxf(x, dpp_mov_f<0x112>(x));  // row_shr:2
    x = fmaxf(x, dpp_mov_f<0x114>(x));  // row_shr:4
    x = fmaxf(x, dpp_mov_f<0x118>(x));  // row_shr:8
    x = fmaxf(x, dpp_mov_f<0x142>(x));  // row_bcast:15
    x = fmaxf(x, dpp_mov_f<0x143>(x));  // row_bcast:31
    return __int_as_float(__builtin_amdgcn_readlane(__float_as_int(x), 63));
}
__device__ __forceinline__ float readlane0_f(float x) {
    return __int_as_float(__builtin_amdgcn_readfirstlane(__float_as_int(x)));
}

// ---------------------------------------------------------------------------
// Kernel A: emissions = hidden @ W + b.  (round-2 version, ~near roofline;
// unchanged — cross-round accounting shows gemm is not the lever.)
// ---------------------------------------------------------------------------
#define BK_ 32
#define BM_ 64
#define P_ 66
__global__ __launch_bounds__(256) void gemm_emis(const float* __restrict__ hidden,
                                                 const float* __restrict__ W,
                                                 const float* __restrict__ bias,
                                                 float* __restrict__ emis) {
    __shared__ float At[BK_ * P_];

    const int tid = threadIdx.x;
    const int lane = tid & 63;
    const int wc = __builtin_amdgcn_readfirstlane((tid >> 6) * 16);
    const int rowbase = blockIdx.x * BM_;
    const int srow = tid >> 2;
    const int scol = (tid & 3) * 8;

    float acc[16];
#pragma unroll
    for (int c = 0; c < 16; ++c) acc[c] = bias[wc + c];

    float4 pf0 = *(const float4*)&hidden[(size_t)(rowbase + srow) * H_ + scol];
    float4 pf1 = *(const float4*)&hidden[(size_t)(rowbase + srow) * H_ + scol + 4];

    for (int kb = 0; kb < H_ / BK_; ++kb) {
        __syncthreads();
        At[(scol + 0) * P_ + srow] = pf0.x;
        At[(scol + 1) * P_ + srow] = pf0.y;
        At[(scol + 2) * P_ + srow] = pf0.z;
        At[(scol + 3) * P_ + srow] = pf0.w;
        At[(scol + 4) * P_ + srow] = pf1.x;
        At[(scol + 5) * P_ + srow] = pf1.y;
        At[(scol + 6) * P_ + srow] = pf1.z;
        At[(scol + 7) * P_ + srow] = pf1.w;
        __syncthreads();
        if (kb + 1 < H_ / BK_) {
            pf0 = *(const float4*)&hidden[(size_t)(rowbase + srow) * H_ +
                                          (kb + 1) * BK_ + scol];
            pf1 = *(const float4*)&hidden[(size_t)(rowbase + srow) * H_ +
                                          (kb + 1) * BK_ + scol + 4];
        }
        const float* Wk = &W[(kb * BK_) * K_ + wc];
#pragma unroll 8
        for (int h = 0; h < BK_; ++h) {
            float a = At[h * P_ + lane];
            float4 w0 = *(const float4*)&Wk[h * K_ + 0];
            float4 w1 = *(const float4*)&Wk[h * K_ + 4];
            float4 w2 = *(const float4*)&Wk[h * K_ + 8];
            float4 w3 = *(const float4*)&Wk[h * K_ + 12];
            acc[0]  += a * w0.x;  acc[1]  += a * w0.y;
            acc[2]  += a * w0.z;  acc[3]  += a * w0.w;
            acc[4]  += a * w1.x;  acc[5]  += a * w1.y;
            acc[6]  += a * w1.z;  acc[7]  += a * w1.w;
            acc[8]  += a * w2.x;  acc[9]  += a * w2.y;
            acc[10] += a * w2.z;  acc[11] += a * w2.w;
            acc[12] += a * w3.x;  acc[13] += a * w3.y;
            acc[14] += a * w3.z;  acc[15] += a * w3.w;
        }
    }

    float* e = &emis[(size_t)(rowbase + lane) * K_ + wc];
#pragma unroll
    for (int q = 0; q < 4; ++q)
        *(float4*)&e[q * 4] = make_float4(acc[q * 4], acc[q * 4 + 1],
                                          acc[q * 4 + 2], acc[q * 4 + 3]);
}

// ---------------------------------------------------------------------------
// Kernel B: fused CRF.  Round 5: DPP ROTATION scan. Evidence so far: readlane
// all-to-all ~1320cy/step (r0, throughput-bound per r3's reorder-null); LDS+
// barrier distributed exchange ALSO ~1320cy/step (r4). New mechanism: keep
// p[j]/v[j] in lane j and hop the vector with v_mov_dpp wave_ror/rol:1 (full-
// rate VALU, ~4cy/hop, no crossbar / DS / barrier). Two opposite chains of
// 32/31 hops; per-lane pre-rotated transition table Er[64] in VGPRs. Rotation
// direction probed at runtime (rotate lane-id, read lane 0) and folded into
// the Er index. Viterbi max-set identical -> bit-identical decode; forward
// dot reordered (absorbed; r4 passed with absmax 0.0). Shell/backtrack = r0.
// ---------------------------------------------------------------------------
__global__ __launch_bounds__(128, 1) void crf_kernel(const float* __restrict__ emis,
                                                     const int* __restrict__ masks,
                                                     const int* __restrict__ target,
                                                     const float* __restrict__ trans,
                                                     float* __restrict__ out) {
    __shared__ __align__(16) float ebuf[T_ * K_];   // 64 KB emissions for batch b
    __shared__ __align__(16) float vbuf[T_ * K_];   // 64 KB viterbi v-history
    __shared__ float tbuf[K_ * 65];                 // padded trans rows (backtrack)

    const int tid = threadIdx.x;
    const int lane = tid & 63;
    const int b = blockIdx.x;
    const float* eb = emis + (size_t)b * (T_ * K_);

    // stage emissions: 4096 float4s over 128 threads
    {
        const float4* src = (const float4*)eb;
        float4* dst = (float4*)ebuf;
#pragma unroll
        for (int k = 0; k < 32; ++k) dst[tid + k * 128] = src[tid + k * 128];
    }
    int sl = 0;
#pragma unroll
    for (int k = 0; k < 4; ++k) sl += masks[b * T_ + lane + k * 64];
#pragma unroll
    for (int m = 32; m; m >>= 1) sl += __shfl_xor(sl, m, 64);
    const int seq_len = sl;

    // probe rotation directions (uniform): after one wave_ror:1 hop, lane j
    // holds value from lane (j + dR) & 63; same for wave_rol:1 -> dL.
    const int dR = __builtin_amdgcn_readfirstlane(dpp_mov_i<0x13C>(lane)) & 63;
    const int dL = __builtin_amdgcn_readfirstlane(dpp_mov_i<0x134>(lane)) & 63;

    __syncthreads();

    if (tid < 64) {
        // ================= forward (wave 0), delayed normalization ==========
        // Er[0]=self; Er[r] (r=1..32) for ror-chain hop r; Er[32+s] (s=1..31)
        // for rol-chain hop s. Er[r] = exp(trans[src][j]), src=(j+r*d)&63.
        float Er[64];
        Er[0] = __expf(trans[lane * K_ + lane]);
#pragma unroll
        for (int r = 1; r <= 32; ++r)
            Er[r] = __expf(trans[(((unsigned)(lane + r * dR)) & 63) * K_ + lane]);
#pragma unroll
        for (int s = 1; s <= 31; ++s)
            Er[32 + s] = __expf(trans[(((unsigned)(lane + s * dL)) & 63) * K_ + lane]);

        float e_c = ebuf[lane];
        float e00 = readlane0_f(e_c);
        float p = __expf(e_c - e00);     // e^{alpha_0} = p * e^C
        float C = e00;
        float logD0prev = 0.f;
        float e_n = ebuf[K_ + lane];
        float en0 = readlane0_f(e_n);
        float xg = __expf(e_n - en0);    // x * g

        for (int t = 1; t < T_; ++t) {
            float e_f = (t < T_ - 1) ? ebuf[(t + 1) * K_ + lane] : 0.f;
            float pr = p, pl = p;
            float a0 = p * Er[0], a1 = 0.f, a2 = 0.f, a3 = 0.f;
#define HR(r, acc) { pr = dpp_mov_f<0x13C>(pr); acc = fmaf(pr, Er[r], acc); }
#define HL(s, acc) { pl = dpp_mov_f<0x134>(pl); acc = fmaf(pl, Er[32 + (s)], acc); }
            HR(1, a1)   HL(1, a2)
            HR(2, a3)   HL(2, a0)
            HR(3, a1)   HL(3, a2)
            HR(4, a3)   HL(4, a0)
            HR(5, a1)   HL(5, a2)
            HR(6, a3)   HL(6, a0)
            HR(7, a1)   HL(7, a2)
            HR(8, a3)   HL(8, a0)
            HR(9, a1)   HL(9, a2)
            HR(10, a3)  HL(10, a0)
            HR(11, a1)  HL(11, a2)
            HR(12, a3)  HL(12, a0)
            HR(13, a1)  HL(13, a2)
            HR(14, a3)  HL(14, a0)
            HR(15, a1)  HL(15, a2)
            HR(16, a3)  HL(16, a0)
            HR(17, a1)  HL(17, a2)
            HR(18, a3)  HL(18, a0)
            HR(19, a1)  HL(19, a2)
            HR(20, a3)  HL(20, a0)
            HR(21, a1)  HL(21, a2)
            HR(22, a3)  HL(22, a0)
            HR(23, a1)  HL(23, a2)
            HR(24, a3)  HL(24, a0)
            HR(25, a1)  HL(25, a2)
            HR(26, a3)  HL(26, a0)
            HR(27, a1)  HL(27, a2)
            HR(28, a3)  HL(28, a0)
            HR(29, a1)  HL(29, a2)
            HR(30, a3)  HL(30, a0)
            HR(31, a1)  HL(31, a2)
            HR(32, a3)
#undef HR
#undef HL
            float D = (a0 + a1) + (a2 + a3);
            float pnew = D * xg;         // only on-chain op after the dot
            if (t < seq_len) { p = pnew; C += en0 + logD0prev; }
            // off-chain prep for next step
            float D0 = readlane0_f(D);
            logD0prev = __logf(D0);
            float gn = __fdividef(1.f, D0);
            en0 = readlane0_f(e_f);
            xg = __expf(e_f - en0) * gn;
            e_n = e_f;
        }
        float rs = p;
#pragma unroll
        for (int m = 32; m; m >>= 1) rs += __shfl_xor(rs, m, 64);
        float log_norm = C + __logf(rs);

        // ---------------- sequence score ----------------
        float sc = 0.f;
#pragma unroll
        for (int k = 0; k < 4; ++k) {
            int t = lane + k * 64;
            if (t < seq_len) {
                int tg = target[b * T_ + t];
                sc += ebuf[t * K_ + tg];
                if (t >= 1) sc += trans[target[b * T_ + t - 1] * K_ + tg];
            }
        }
#pragma unroll
        for (int m = 32; m; m >>= 1) sc += __shfl_xor(sc, m, 64);
        if (lane == 0) out[BT_ + b] = sc - log_norm;
    } else {
        // ================= Viterbi (wave 1): DPP rotation max-plus ==========
        float Tr[64];
        Tr[0] = trans[lane * K_ + lane];
#pragma unroll
        for (int r = 1; r <= 32; ++r)
            Tr[r] = trans[(((unsigned)(lane + r * dR)) & 63) * K_ + lane];
#pragma unroll
        for (int s = 1; s <= 31; ++s)
            Tr[32 + s] = trans[(((unsigned)(lane + s * dL)) & 63) * K_ + lane];
        for (int idx = lane; idx < K_ * K_; idx += 64)
            tbuf[(idx >> 6) * 65 + (idx & 63)] = trans[idx];

        float v = ebuf[lane];
        vbuf[lane] = v;
        float e_n = ebuf[K_ + lane];
        for (int t = 1; t < T_; ++t) {
            float e_f = (t < T_ - 1) ? ebuf[(t + 1) * K_ + lane] : 0.f;
            float vr = v, vl = v;
            float m0 = v + Tr[0];
            float m1 = -3.4e38f, m2 = -3.4e38f, m3 = -3.4e38f;
#define WR(r, macc) { vr = dpp_mov_f<0x13C>(vr); macc = fmaxf(macc, vr + Tr[r]); }
#define WL(s, macc) { vl = dpp_mov_f<0x134>(vl); macc = fmaxf(macc, vl + Tr[32 + (s)]); }
            WR(1, m1)   WL(1, m2)
            WR(2, m3)   WL(2, m0)
            WR(3, m1)   WL(3, m2)
            WR(4, m3)   WL(4, m0)
            WR(5, m1)   WL(5, m2)
            WR(6, m3)   WL(6, m0)
            WR(7, m1)   WL(7, m2)
            WR(8, m3)   WL(8, m0)
            WR(9, m1)   WL(9, m2)
            WR(10, m3)  WL(10, m0)
            WR(11, m1)  WL(11, m2)
            WR(12, m3)  WL(12, m0)
            WR(13, m1)  WL(13, m2)
            WR(14, m3)  WL(14, m0)
            WR(15, m1)  WL(15, m2)
            WR(16, m3)  WL(16, m0)
            WR(17, m1)  WL(17, m2)
            WR(18, m3)  WL(18, m0)
            WR(19, m1)  WL(19, m2)
            WR(20, m3)  WL(20, m0)
            WR(21, m1)  WL(21, m2)
            WR(22, m3)  WL(22, m0)
            WR(23, m1)  WL(23, m2)
            WR(24, m3)  WL(24, m0)
            WR(25, m1)  WL(25, m2)
            WR(26, m3)  WL(26, m0)
            WR(27, m1)  WL(27, m2)
            WR(28, m3)  WL(28, m0)
            WR(29, m1)  WL(29, m2)
            WR(30, m3)  WL(30, m0)
            WR(31, m1)  WL(31, m2)
            WR(32, m3)
#undef WR
#undef WL
            float M = fmaxf(fmaxf(m0, m1), fmaxf(m2, m3));
            float vn = M + e_n;
            if (t < seq_len) v = vn;
            vbuf[t * K_ + lane] = v;   // off-chain ds_write (history)
            e_n = e_f;
        }

        // last tag: first index of max over lanes (np.argmax tie rule)
        float M = wave_max64(v);
        unsigned long long ball = __ballot(v >= M);
        int tag = (int)__builtin_ctzll(ball);

        int path[4];
#pragma unroll
        for (int k = 0; k < 4; ++k) path[k] = 0;
        if (lane == ((T_ - 1) & 63)) path[(T_ - 1) >> 6] = tag;

        float vpre = vbuf[(T_ - 2) * K_ + lane];
        for (int t = T_ - 1; t >= 1; --t) {
            float vnext = (t >= 2) ? vbuf[(t - 2) * K_ + lane] : 0.f;
            if (t < seq_len) {
                float s = vpre + tbuf[lane * 65 + tag];
                float Ms = wave_max64(s);
                unsigned long long bl = __ballot(s >= Ms);
                tag = (int)__builtin_ctzll(bl);
            }
            int pidx = t - 1;
            if (lane == (pidx & 63)) path[pidx >> 6] = tag;
            vpre = vnext;
        }
#pragma unroll
        for (int k = 0; k < 4; ++k) {
            int t = lane + k * 64;
            out[b * T_ + t] = (t < seq_len) ? (float)path[k] : 0.f;
        }
    }
}

// ---------------------------------------------------------------------------
extern "C" void kernel_launch(void* const* d_in, const int* in_sizes, int n_in,
                              void* d_out, int out_size, void* d_ws, size_t ws_size,
                              hipStream_t stream) {
    const float* hidden = (const float*)d_in[0];
    const int* masks    = (const int*)d_in[1];
    const int* target   = (const int*)d_in[2];
    const float* W      = (const float*)d_in[3];
    const float* bias   = (const float*)d_in[4];
    const float* trans  = (const float*)d_in[5];
    float* out = (float*)d_out;
    float* emis = (float*)d_ws;

    gemm_emis<<<dim3(BT_ / BM_), dim3(256), 0, stream>>>(hidden, W, bias, emis);
    crf_kernel<<<dim3(B_), dim3(128), 0, stream>>>(emis, masks, target, trans, out);
}